// Round 1
// baseline (505.425 us; speedup 1.0000x reference)
//
#include <hip/hip_runtime.h>
#include <math.h>

using bf16 = __bf16;
using bf16x4 = __attribute__((ext_vector_type(4))) __bf16;
using bf16x8 = __attribute__((ext_vector_type(8))) __bf16;
using f32x4 = __attribute__((ext_vector_type(4))) float;

static constexpr int B_ = 2, S_ = 2048, H_ = 1024, NH_ = 16, HD_ = 64;
static constexpr int M_ = B_ * S_;                 // 4096 rows of X
static constexpr size_t SZX = (size_t)M_ * H_;     // 4,194,304 elems
static constexpr size_t SZW = (size_t)H_ * H_;     // 1,048,576 elems

__device__ __forceinline__ f32x4 mfma16(bf16x8 a, bf16x8 b, f32x4 c) {
    return __builtin_amdgcn_mfma_f32_16x16x32_bf16(a, b, c, 0, 0, 0);
}

// ---------------- split fp32 -> bf16 hi/lo planes ----------------
__global__ __launch_bounds__(256) void split_kernel(const float* __restrict__ x,
                                                    bf16* __restrict__ hi,
                                                    bf16* __restrict__ lo, int n4) {
    int i = blockIdx.x * 256 + threadIdx.x;
    if (i >= n4) return;
    float4 v = ((const float4*)x)[i];
    bf16x4 h, l;
    h.x = (bf16)v.x; l.x = (bf16)(v.x - (float)h.x);
    h.y = (bf16)v.y; l.y = (bf16)(v.y - (float)h.y);
    h.z = (bf16)v.z; l.z = (bf16)(v.z - (float)h.z);
    h.w = (bf16)v.w; l.w = (bf16)(v.w - (float)h.w);
    ((bf16x4*)hi)[i] = h;
    ((bf16x4*)lo)[i] = l;
}

// ---------------- projection GEMM: O[m,n] = sum_k X[m,k] W[n,k] + b[n] ----
// tile 128(M) x 64(N), BK=64, block=256 (4 waves, each wave 32 rows x 64 cols)
// split-bf16: acc += Xh*Wh + Xh*Wl + Xl*Wh
// LDS XOR swizzle on 8-elem k-blocks: phys_block = block ^ (row & 7)
__global__ __launch_bounds__(256) void proj_kernel(const bf16* __restrict__ Xh, const bf16* __restrict__ Xl,
                                                   const bf16* __restrict__ Wh, const bf16* __restrict__ Wl,
                                                   const float* __restrict__ bias,
                                                   bf16* __restrict__ Oh, bf16* __restrict__ Ol) {
    __shared__ alignas(16) bf16 sXh[128][64];
    __shared__ alignas(16) bf16 sXl[128][64];
    __shared__ alignas(16) bf16 sWh[64][64];
    __shared__ alignas(16) bf16 sWl[64][64];

    const int t = threadIdx.x;
    const int row0 = blockIdx.y * 128;
    const int col0 = blockIdx.x * 64;
    const int w = t >> 6, lane = t & 63;
    const int quad = lane >> 4, c = lane & 15;

    f32x4 acc[2][4] = {};

    for (int k0 = 0; k0 < H_; k0 += 64) {
        // stage X 128x64 (hi+lo): 1024 8-elem blocks, 4 per thread
#pragma unroll
        for (int i = 0; i < 4; ++i) {
            int idx = t + i * 256;
            int r = idx >> 3, bb = idx & 7;
            size_t g = (size_t)(row0 + r) * H_ + k0 + bb * 8;
            int pc = (bb ^ (r & 7)) * 8;
            *(bf16x8*)&sXh[r][pc] = *(const bf16x8*)(Xh + g);
            *(bf16x8*)&sXl[r][pc] = *(const bf16x8*)(Xl + g);
        }
        // stage W 64x64 (hi+lo)
#pragma unroll
        for (int i = 0; i < 2; ++i) {
            int idx = t + i * 256;
            int r = idx >> 3, bb = idx & 7;
            size_t g = (size_t)(col0 + r) * H_ + k0 + bb * 8;
            int pc = (bb ^ (r & 7)) * 8;
            *(bf16x8*)&sWh[r][pc] = *(const bf16x8*)(Wh + g);
            *(bf16x8*)&sWl[r][pc] = *(const bf16x8*)(Wl + g);
        }
        __syncthreads();
#pragma unroll
        for (int ks = 0; ks < 2; ++ks) {
            int pc = ((ks * 4 + quad) ^ (c & 7)) * 8;
            bf16x8 ah[2], al[2];
#pragma unroll
            for (int g = 0; g < 2; ++g) {
                int r = w * 32 + g * 16 + c;
                ah[g] = *(const bf16x8*)&sXh[r][pc];
                al[g] = *(const bf16x8*)&sXl[r][pc];
            }
#pragma unroll
            for (int n = 0; n < 4; ++n) {
                int rw = n * 16 + c;
                bf16x8 bh = *(const bf16x8*)&sWh[rw][pc];
                bf16x8 bl = *(const bf16x8*)&sWl[rw][pc];
#pragma unroll
                for (int g = 0; g < 2; ++g) {
                    acc[g][n] = mfma16(ah[g], bh, acc[g][n]);
                    acc[g][n] = mfma16(ah[g], bl, acc[g][n]);
                    acc[g][n] = mfma16(al[g], bh, acc[g][n]);
                }
            }
        }
        __syncthreads();
    }

    // epilogue: add bias, split to hi/lo, write [B,NH,S,HD]
#pragma unroll
    for (int g = 0; g < 2; ++g) {
#pragma unroll
        for (int n = 0; n < 4; ++n) {
            int col = col0 + n * 16 + c;
            float bv = bias[col];
            int hh = col >> 6, d = col & 63;
#pragma unroll
            for (int r = 0; r < 4; ++r) {
                int rowg = row0 + w * 32 + g * 16 + quad * 4 + r;
                int bb = rowg >> 11, ss = rowg & (S_ - 1);
                float v = acc[g][n][r] + bv;
                bf16 h = (bf16)v;
                bf16 l = (bf16)(v - (float)h);
                size_t o = ((size_t)(bb * NH_ + hh) * S_ + ss) * HD_ + d;
                Oh[o] = h;
                Ol[o] = l;
            }
        }
    }
}

// ---------------- flash attention ----------------
// block = (b,h,Q-tile of 64 rows); 4 waves x 16 Q-rows each; K/V tiles of 64 keys
// P (post-softmax) reuses the K LDS buffers (barrier in between); V staged transposed.
__global__ __launch_bounds__(256) void attn_kernel(const bf16* __restrict__ Qh, const bf16* __restrict__ Ql,
                                                   const bf16* __restrict__ Kh, const bf16* __restrict__ Kl,
                                                   const bf16* __restrict__ Vh, const bf16* __restrict__ Vl,
                                                   const float* __restrict__ mask,
                                                   float* __restrict__ out) {
    __shared__ alignas(16) bf16 sQh[64][64];
    __shared__ alignas(16) bf16 sQl[64][64];
    __shared__ alignas(16) bf16 sKPh[64][64];  // K tile, then reused for P
    __shared__ alignas(16) bf16 sKPl[64][64];
    __shared__ alignas(16) bf16 sVh[64][64];   // V transposed: [dim][key]
    __shared__ alignas(16) bf16 sVl[64][64];

    const int t = threadIdx.x;
    const int qt = blockIdx.x;
    const int bh = blockIdx.y;
    const int b = bh >> 4, hh = bh & 15;
    const size_t base = (size_t)bh * S_ * HD_;
    const int w = t >> 6, lane = t & 63;
    const int quad = lane >> 4, c = lane & 15;

    // stage Q tile once
#pragma unroll
    for (int i = 0; i < 2; ++i) {
        int idx = t + i * 256;
        int r = idx >> 3, bb = idx & 7;
        size_t g = base + (size_t)(qt * 64 + r) * 64 + bb * 8;
        int pc = (bb ^ (r & 7)) * 8;
        *(bf16x8*)&sQh[r][pc] = *(const bf16x8*)(Qh + g);
        *(bf16x8*)&sQl[r][pc] = *(const bf16x8*)(Ql + g);
    }

    float mrow[4] = {-INFINITY, -INFINITY, -INFINITY, -INFINITY};
    float lrow[4] = {0.f, 0.f, 0.f, 0.f};
    f32x4 o[4] = {};

    for (int kt = 0; kt < S_ / 64; ++kt) {
        // stage K tile [key][dim]
#pragma unroll
        for (int i = 0; i < 2; ++i) {
            int idx = t + i * 256;
            int r = idx >> 3, bb = idx & 7;
            size_t g = base + (size_t)(kt * 64 + r) * 64 + bb * 8;
            int pc = (bb ^ (r & 7)) * 8;
            *(bf16x8*)&sKPh[r][pc] = *(const bf16x8*)(Kh + g);
            *(bf16x8*)&sKPl[r][pc] = *(const bf16x8*)(Kl + g);
        }
        // stage V transposed -> sV[dim][key]
#pragma unroll
        for (int i = 0; i < 2; ++i) {
            int idx = t + i * 256;
            int key = idx >> 3, db = idx & 7;
            size_t g = base + (size_t)(kt * 64 + key) * 64 + db * 8;
            bf16x8 vh = *(const bf16x8*)(Vh + g);
            bf16x8 vl = *(const bf16x8*)(Vl + g);
            int kb = key >> 3, ko = key & 7;
#pragma unroll
            for (int j = 0; j < 8; ++j) {
                int dim = db * 8 + j;
                int pc = (kb ^ (dim & 7)) * 8 + ko;
                sVh[dim][pc] = vh[j];
                sVl[dim][pc] = vl[j];
            }
        }
        __syncthreads();

        // S = Q K^T  (16 q-rows x 64 keys per wave)
        f32x4 s[4] = {};
#pragma unroll
        for (int ks = 0; ks < 2; ++ks) {
            int pc = ((ks * 4 + quad) ^ (c & 7)) * 8;
            int rq = w * 16 + c;
            bf16x8 ah = *(const bf16x8*)&sQh[rq][pc];
            bf16x8 al = *(const bf16x8*)&sQl[rq][pc];
#pragma unroll
            for (int n = 0; n < 4; ++n) {
                int rk = n * 16 + c;
                bf16x8 bh = *(const bf16x8*)&sKPh[rk][pc];
                bf16x8 bl = *(const bf16x8*)&sKPl[rk][pc];
                s[n] = mfma16(ah, bh, s[n]);
                s[n] = mfma16(ah, bl, s[n]);
                s[n] = mfma16(al, bh, s[n]);
            }
        }

        // online softmax (fp32, registers + 16-lane shuffles)
        float sv[4][4];
#pragma unroll
        for (int n = 0; n < 4; ++n) {
            float mk = mask[b * S_ + kt * 64 + n * 16 + c];
#pragma unroll
            for (int r = 0; r < 4; ++r) sv[n][r] = s[n][r] * 0.125f + mk;
        }
#pragma unroll
        for (int r = 0; r < 4; ++r) {
            float rm = fmaxf(fmaxf(sv[0][r], sv[1][r]), fmaxf(sv[2][r], sv[3][r]));
            rm = fmaxf(rm, __shfl_xor(rm, 1));
            rm = fmaxf(rm, __shfl_xor(rm, 2));
            rm = fmaxf(rm, __shfl_xor(rm, 4));
            rm = fmaxf(rm, __shfl_xor(rm, 8));
            float mnew = fmaxf(mrow[r], rm);
            float alpha = __expf(mrow[r] - mnew);   // first iter: exp(-inf)=0
            mrow[r] = mnew;
            float rs = 0.f;
#pragma unroll
            for (int n = 0; n < 4; ++n) {
                float p = __expf(sv[n][r] - mnew);
                sv[n][r] = p;
                rs += p;
            }
            rs += __shfl_xor(rs, 1);
            rs += __shfl_xor(rs, 2);
            rs += __shfl_xor(rs, 4);
            rs += __shfl_xor(rs, 8);
            lrow[r] = lrow[r] * alpha + rs;
#pragma unroll
            for (int n = 0; n < 4; ++n) o[n][r] *= alpha;
        }

        __syncthreads();  // all waves done reading K before P overwrites it

        // write P (hi/lo) into the K buffers; rows are wave-private
#pragma unroll
        for (int n = 0; n < 4; ++n) {
            int key = n * 16 + c;
            int kb = key >> 3, ko = key & 7;
#pragma unroll
            for (int r = 0; r < 4; ++r) {
                int pr = w * 16 + quad * 4 + r;
                float p = sv[n][r];
                bf16 ph = (bf16)p;
                bf16 pl = (bf16)(p - (float)ph);
                int pc = (kb ^ (pr & 7)) * 8 + ko;
                sKPh[pr][pc] = ph;
                sKPl[pr][pc] = pl;
            }
        }

        // O += P V   (A = P in A-layout from LDS, B = V^T rows)
#pragma unroll
        for (int ks = 0; ks < 2; ++ks) {
            int pc = ((ks * 4 + quad) ^ (c & 7)) * 8;
            int rp = w * 16 + c;
            bf16x8 ah = *(const bf16x8*)&sKPh[rp][pc];
            bf16x8 al = *(const bf16x8*)&sKPl[rp][pc];
#pragma unroll
            for (int n = 0; n < 4; ++n) {
                int rv = n * 16 + c;
                bf16x8 bh = *(const bf16x8*)&sVh[rv][pc];
                bf16x8 bl = *(const bf16x8*)&sVl[rv][pc];
                o[n] = mfma16(ah, bh, o[n]);
                o[n] = mfma16(ah, bl, o[n]);
                o[n] = mfma16(al, bh, o[n]);
            }
        }
        __syncthreads();
    }

    // epilogue: ctx = O / l, write [B,S,H] fp32
#pragma unroll
    for (int n = 0; n < 4; ++n) {
#pragma unroll
        for (int r = 0; r < 4; ++r) {
            int srow = qt * 64 + w * 16 + quad * 4 + r;
            float val = o[n][r] / lrow[r];
            out[((size_t)b * S_ + srow) * H_ + hh * 64 + n * 16 + c] = val;
        }
    }
}

// ---------------- launch ----------------
extern "C" void kernel_launch(void* const* d_in, const int* in_sizes, int n_in,
                              void* d_out, int out_size, void* d_ws, size_t ws_size,
                              hipStream_t stream) {
    const float* query = (const float*)d_in[0];
    const float* key   = (const float*)d_in[1];
    const float* value = (const float*)d_in[2];
    const float* mask  = (const float*)d_in[3];
    const float* Wq    = (const float*)d_in[4];
    const float* bq    = (const float*)d_in[5];
    const float* Wk    = (const float*)d_in[6];
    const float* bk    = (const float*)d_in[7];
    const float* Wv    = (const float*)d_in[8];
    const float* bv    = (const float*)d_in[9];
    float* out = (float*)d_out;

    bf16* p = (bf16*)d_ws;
    bf16* xqh = p; p += SZX; bf16* xql = p; p += SZX;
    bf16* xkh = p; p += SZX; bf16* xkl = p; p += SZX;
    bf16* xvh = p; p += SZX; bf16* xvl = p; p += SZX;
    bf16* wqh = p; p += SZW; bf16* wql = p; p += SZW;
    bf16* wkh = p; p += SZW; bf16* wkl = p; p += SZW;
    bf16* wvh = p; p += SZW; bf16* wvl = p; p += SZW;
    bf16* qh  = p; p += SZX; bf16* ql  = p; p += SZX;
    bf16* kh  = p; p += SZX; bf16* kl  = p; p += SZX;
    bf16* vh  = p; p += SZX; bf16* vl  = p; p += SZX;
    // total ws use: 113,246,208 bytes

    split_kernel<<<(int)(SZX / 1024), 256, 0, stream>>>(query, xqh, xql, (int)(SZX / 4));
    split_kernel<<<(int)(SZX / 1024), 256, 0, stream>>>(key,   xkh, xkl, (int)(SZX / 4));
    split_kernel<<<(int)(SZX / 1024), 256, 0, stream>>>(value, xvh, xvl, (int)(SZX / 4));
    split_kernel<<<(int)(SZW / 1024), 256, 0, stream>>>(Wq, wqh, wql, (int)(SZW / 4));
    split_kernel<<<(int)(SZW / 1024), 256, 0, stream>>>(Wk, wkh, wkl, (int)(SZW / 4));
    split_kernel<<<(int)(SZW / 1024), 256, 0, stream>>>(Wv, wvh, wvl, (int)(SZW / 4));

    dim3 pg(H_ / 64, M_ / 128);
    proj_kernel<<<pg, 256, 0, stream>>>(xqh, xql, wqh, wql, bq, qh, ql);
    proj_kernel<<<pg, 256, 0, stream>>>(xkh, xkl, wkh, wkl, bk, kh, kl);
    proj_kernel<<<pg, 256, 0, stream>>>(xvh, xvl, wvh, wvl, bv, vh, vl);

    dim3 ag(S_ / 64, B_ * NH_);
    attn_kernel<<<ag, 256, 0, stream>>>(qh, ql, kh, kl, vh, vl, mask, out);
}

// Round 2
// 297.159 us; speedup vs baseline: 1.7009x; 1.7009x over previous
//
#include <hip/hip_runtime.h>
#include <math.h>

using bf16 = __bf16;
using bf16x4 = __attribute__((ext_vector_type(4))) __bf16;
using bf16x8 = __attribute__((ext_vector_type(8))) __bf16;
using f32x4 = __attribute__((ext_vector_type(4))) float;

static constexpr int B_ = 2, S_ = 2048, H_ = 1024, NH_ = 16, HD_ = 64;
static constexpr int M_ = B_ * S_;                 // 4096 rows of X
static constexpr size_t SZX = (size_t)M_ * H_;     // 4,194,304 elems
static constexpr size_t SZW = (size_t)H_ * H_;     // 1,048,576 elems

__device__ __forceinline__ f32x4 mfma32(bf16x8 a, bf16x8 b, f32x4 c) {
    return __builtin_amdgcn_mfma_f32_16x16x32_bf16(a, b, c, 0, 0, 0);
}

// async 16B global -> LDS (wave-uniform LDS base + lane*16; global addr per-lane)
typedef const __attribute__((address_space(1))) unsigned int* gas_t;
typedef __attribute__((address_space(3))) unsigned int* las_t;
__device__ __forceinline__ void load16_lds(const bf16* g, bf16* lds_base) {
    __builtin_amdgcn_global_load_lds((gas_t)g, (las_t)lds_base, 16, 0, 0);
}

// ---------------- split fp32 -> bf16 hi/lo planes (3 tensors per launch) ----
__global__ __launch_bounds__(256) void split3_kernel(
    const float* __restrict__ a0, const float* __restrict__ a1, const float* __restrict__ a2,
    bf16* __restrict__ h0, bf16* __restrict__ l0,
    bf16* __restrict__ h1, bf16* __restrict__ l1,
    bf16* __restrict__ h2, bf16* __restrict__ l2, int n4) {
    int z = blockIdx.y;
    const float* x = z == 0 ? a0 : z == 1 ? a1 : a2;
    bf16* hp = z == 0 ? h0 : z == 1 ? h1 : h2;
    bf16* lp = z == 0 ? l0 : z == 1 ? l1 : l2;
    int i = blockIdx.x * 256 + threadIdx.x;
    if (i >= n4) return;
    f32x4 v = ((const f32x4*)x)[i];
    bf16x4 h, l;
#pragma unroll
    for (int j = 0; j < 4; ++j) {
        h[j] = (bf16)v[j];
        l[j] = (bf16)(v[j] - (float)h[j]);
    }
    ((bf16x4*)hp)[i] = h;
    ((bf16x4*)lp)[i] = l;
}

// ---------------- fused QKV projection GEMM -------------------------------
// O[m,n] = sum_k X[m,k] W[n,k] + b[n]; split-bf16 3-term. Tile 128x128,
// 4 waves each 64x64. which = blockIdx.x>>3 selects q/k/v. q pre-scaled 1/8.
// Output layout [B,NH,S,HD] hi(+lo); V writes hi only.
__global__ __launch_bounds__(256, 2) void proj_kernel(
    const bf16* __restrict__ xqh, const bf16* __restrict__ xql,
    const bf16* __restrict__ xkh, const bf16* __restrict__ xkl,
    const bf16* __restrict__ xvh, const bf16* __restrict__ xvl,
    const bf16* __restrict__ wqh, const bf16* __restrict__ wql,
    const bf16* __restrict__ wkh, const bf16* __restrict__ wkl,
    const bf16* __restrict__ wvh, const bf16* __restrict__ wvl,
    const float* __restrict__ bq, const float* __restrict__ bk, const float* __restrict__ bv,
    bf16* __restrict__ qh, bf16* __restrict__ ql,
    bf16* __restrict__ kh, bf16* __restrict__ kl, bf16* __restrict__ vh) {
    __shared__ alignas(16) bf16 sXh[128][64];
    __shared__ alignas(16) bf16 sXl[128][64];
    __shared__ alignas(16) bf16 sWh[128][64];
    __shared__ alignas(16) bf16 sWl[128][64];

    const int t = threadIdx.x, w = t >> 6, lane = t & 63, c = lane & 15, quad = lane >> 4;
    const int which = blockIdx.x >> 3;
    const int col0 = (blockIdx.x & 7) * 128;
    const int row0 = blockIdx.y * 128;
    const bf16* Xh = which == 0 ? xqh : which == 1 ? xkh : xvh;
    const bf16* Xl = which == 0 ? xql : which == 1 ? xkl : xvl;
    const bf16* Wh = which == 0 ? wqh : which == 1 ? wkh : wvh;
    const bf16* Wl = which == 0 ? wql : which == 1 ? wkl : wvl;

    const int wm = (w & 1) * 64, wn = (w >> 1) * 64;
    f32x4 acc[4][4] = {};

    for (int k0 = 0; k0 < H_; k0 += 64) {
        if (k0) __syncthreads();
#pragma unroll
        for (int i = 0; i < 4; ++i) {
            int r = 8 * w + 32 * i + (lane >> 3);
            int cb = (lane & 7) ^ ((lane >> 3) & 7);   // swizzle folded into global addr
            size_t gx = (size_t)(row0 + r) * H_ + k0 + cb * 8;
            size_t gw = (size_t)(col0 + r) * H_ + k0 + cb * 8;
            load16_lds(Xh + gx, &sXh[8 * w + 32 * i][0]);
            load16_lds(Xl + gx, &sXl[8 * w + 32 * i][0]);
            load16_lds(Wh + gw, &sWh[8 * w + 32 * i][0]);
            load16_lds(Wl + gw, &sWl[8 * w + 32 * i][0]);
        }
        __syncthreads();
#pragma unroll
        for (int ks = 0; ks < 2; ++ks) {
            const int ph = ((ks * 4 + quad) ^ (c & 7)) * 8;
            bf16x8 bhf[4], blf[4];
#pragma unroll
            for (int ng = 0; ng < 4; ++ng) {
                int rw = wn + ng * 16 + c;
                bhf[ng] = *(const bf16x8*)&sWh[rw][ph];
                blf[ng] = *(const bf16x8*)&sWl[rw][ph];
            }
#pragma unroll
            for (int mg = 0; mg < 4; ++mg) {
                int rx = wm + mg * 16 + c;
                bf16x8 ah = *(const bf16x8*)&sXh[rx][ph];
                bf16x8 al = *(const bf16x8*)&sXl[rx][ph];
#pragma unroll
                for (int ng = 0; ng < 4; ++ng) {
                    acc[mg][ng] = mfma32(ah, bhf[ng], acc[mg][ng]);
                    acc[mg][ng] = mfma32(ah, blf[ng], acc[mg][ng]);
                    acc[mg][ng] = mfma32(al, bhf[ng], acc[mg][ng]);
                }
            }
        }
    }

    const float* bias = which == 0 ? bq : which == 1 ? bk : bv;
    bf16* Oh = which == 0 ? qh : which == 1 ? kh : vh;
    bf16* Ol = which == 0 ? ql : which == 1 ? kl : nullptr;
    const float scale = which == 0 ? 0.125f : 1.0f;
#pragma unroll
    for (int ng = 0; ng < 4; ++ng) {
        int col = col0 + wn + ng * 16 + c;
        float bv_ = bias[col];
        int hh = col >> 6, d = col & 63;
#pragma unroll
        for (int mg = 0; mg < 4; ++mg) {
#pragma unroll
            for (int r4 = 0; r4 < 4; ++r4) {
                int rowg = row0 + wm + mg * 16 + quad * 4 + r4;
                int bb = rowg >> 11, ss = rowg & (S_ - 1);
                float v = (acc[mg][ng][r4] + bv_) * scale;
                bf16 h = (bf16)v;
                size_t o = ((size_t)(bb * NH_ + hh) * S_ + ss) * HD_ + d;
                Oh[o] = h;
                if (Ol) Ol[o] = (bf16)(v - (float)h);
            }
        }
    }
}

// ---------------- V transpose: [bh][s][d] -> [bh][d][s] --------------------
__global__ __launch_bounds__(256) void transpose_v(const bf16* __restrict__ vh,
                                                   bf16* __restrict__ vt) {
    __shared__ unsigned short sT[64][72];   // pad 8: b128-aligned rows
    const int t = threadIdx.x;
    const int s0 = blockIdx.x * 64, bh = blockIdx.y;
    const size_t ib = (size_t)bh * S_ * HD_;
    const size_t ob = (size_t)bh * HD_ * S_;
#pragma unroll
    for (int i = 0; i < 2; ++i) {
        int idx = t + i * 256;
        int sl = idx >> 3, db = idx & 7;
        bf16x8 v = *(const bf16x8*)(vh + ib + (size_t)(s0 + sl) * HD_ + db * 8);
        *(bf16x8*)&sT[sl][db * 8] = v;
    }
    __syncthreads();
#pragma unroll
    for (int i = 0; i < 2; ++i) {
        int idx = t + i * 256;
        int d = idx >> 3, sb = idx & 7;
        bf16x8 v;
#pragma unroll
        for (int j = 0; j < 8; ++j) {
            unsigned short u = sT[sb * 8 + j][d];
            v[j] = *(bf16*)&u;
        }
        *(bf16x8*)(vt + ob + (size_t)d * S_ + s0 + sb * 8) = v;
    }
}

// ---------------- flash attention (S^T formulation) ------------------------
// block: (q-tile 128, bh). 4 waves x 32 q. Q frags in registers.
// S^T = K·Q^T (keys=M, q=N); softmax per q-column; O^T = V^T·P^T with P in
// registers (C-layout of S^T == B-operand k-pattern for 16-key chunks).
__global__ __launch_bounds__(256, 2) void attn_kernel(
    const bf16* __restrict__ Qh, const bf16* __restrict__ Ql,
    const bf16* __restrict__ Kh, const bf16* __restrict__ Kl,
    const bf16* __restrict__ VT, const float* __restrict__ mask,
    float* __restrict__ out) {
    __shared__ alignas(16) bf16 sKh[64][64];
    __shared__ alignas(16) bf16 sKl[64][64];
    __shared__ alignas(16) bf16 sVT[64][64];   // [d][key]

    const int t = threadIdx.x, w = t >> 6, lane = t & 63, c = lane & 15, quad = lane >> 4;
    const int qt = blockIdx.x, bh = blockIdx.y;
    const int b = bh >> 4, hh = bh & 15;
    const size_t qkb = (size_t)bh * S_ * HD_;
    const size_t vtb = (size_t)bh * HD_ * S_;

    // Q fragments (registers, whole K-loop): [nb][ch]
    bf16x8 qfh[2][2], qfl[2][2];
#pragma unroll
    for (int nb = 0; nb < 2; ++nb)
#pragma unroll
        for (int ch = 0; ch < 2; ++ch) {
            int q = qt * 128 + w * 32 + nb * 16 + c;
            size_t g = qkb + (size_t)q * HD_ + ch * 32 + quad * 8;
            qfh[nb][ch] = *(const bf16x8*)(Qh + g);
            qfl[nb][ch] = *(const bf16x8*)(Ql + g);
        }

    f32x4 o[4][2] = {};
    float m_i[2] = {-INFINITY, -INFINITY};
    float l_i[2] = {0.f, 0.f};

    for (int kt = 0; kt < S_ / 64; ++kt) {
        if (kt) __syncthreads();
#pragma unroll
        for (int i = 0; i < 2; ++i) {
            int r = 8 * w + 32 * i + (lane >> 3);
            int cb = (lane & 7) ^ ((lane >> 3) & 7);
            size_t gk = qkb + (size_t)(kt * 64 + r) * HD_ + cb * 8;
            load16_lds(Kh + gk, &sKh[8 * w + 32 * i][0]);
            load16_lds(Kl + gk, &sKl[8 * w + 32 * i][0]);
            size_t gv = vtb + (size_t)r * S_ + kt * 64 + cb * 8;
            load16_lds(VT + gv, &sVT[8 * w + 32 * i][0]);
        }
        __syncthreads();

        // S^T[key][q], wave: 64 keys x 32 q
        f32x4 s[4][2] = {};
#pragma unroll
        for (int ch = 0; ch < 2; ++ch) {
#pragma unroll
            for (int mb = 0; mb < 4; ++mb) {
                int row = mb * 16 + c;
                int ph = ((ch * 4 + quad) ^ (c & 7)) * 8;
                bf16x8 ah = *(const bf16x8*)&sKh[row][ph];
                bf16x8 al = *(const bf16x8*)&sKl[row][ph];
#pragma unroll
                for (int nb = 0; nb < 2; ++nb) {
                    s[mb][nb] = mfma32(ah, qfh[nb][ch], s[mb][nb]);
                    s[mb][nb] = mfma32(ah, qfl[nb][ch], s[mb][nb]);
                    s[mb][nb] = mfma32(al, qfh[nb][ch], s[mb][nb]);
                }
            }
        }

        f32x4 mk[4];
#pragma unroll
        for (int mb = 0; mb < 4; ++mb)
            mk[mb] = *(const f32x4*)(mask + b * S_ + kt * 64 + mb * 16 + quad * 4);

        bf16x4 pf[4][2];   // P fragments [key16-chunk][nb]
#pragma unroll
        for (int nb = 0; nb < 2; ++nb) {
            float sv[4][4];
            float rm = -INFINITY;
#pragma unroll
            for (int mb = 0; mb < 4; ++mb)
#pragma unroll
                for (int r = 0; r < 4; ++r) {
                    float x = s[mb][nb][r] + mk[mb][r];   // q pre-scaled by 1/8
                    sv[mb][r] = x;
                    rm = fmaxf(rm, x);
                }
            rm = fmaxf(rm, __shfl_xor(rm, 16));
            rm = fmaxf(rm, __shfl_xor(rm, 32));
            float mnew = fmaxf(m_i[nb], rm);
            float alpha = __expf(m_i[nb] - mnew);
            m_i[nb] = mnew;
            float rs = 0.f;
#pragma unroll
            for (int mb = 0; mb < 4; ++mb)
#pragma unroll
                for (int r = 0; r < 4; ++r) {
                    float p = __expf(sv[mb][r] - mnew);
                    sv[mb][r] = p;
                    rs += p;
                }
            rs += __shfl_xor(rs, 16);
            rs += __shfl_xor(rs, 32);
            l_i[nb] = l_i[nb] * alpha + rs;
#pragma unroll
            for (int db = 0; db < 4; ++db) o[db][nb] *= alpha;
#pragma unroll
            for (int mb = 0; mb < 4; ++mb) {
                bf16x4 p4;
#pragma unroll
                for (int r = 0; r < 4; ++r) p4[r] = (bf16)sv[mb][r];
                pf[mb][nb] = p4;
            }
        }

        // O^T += V^T · P^T : pack two 16-key chunks into one K=32 MFMA
#pragma unroll
        for (int kcc = 0; kcc < 2; ++kcc) {
#pragma unroll
            for (int db = 0; db < 4; ++db) {
                int row = db * 16 + c;
                int k0 = 2 * kcc, k1 = 2 * kcc + 1;
                bf16x4 a0 = *(const bf16x4*)&sVT[row][((2 * k0 + (quad >> 1)) ^ (c & 7)) * 8 + (quad & 1) * 4];
                bf16x4 a1 = *(const bf16x4*)&sVT[row][((2 * k1 + (quad >> 1)) ^ (c & 7)) * 8 + (quad & 1) * 4];
                bf16x8 af = __builtin_shufflevector(a0, a1, 0, 1, 2, 3, 4, 5, 6, 7);
#pragma unroll
                for (int nb = 0; nb < 2; ++nb) {
                    bf16x8 bf_ = __builtin_shufflevector(pf[k0][nb], pf[k1][nb], 0, 1, 2, 3, 4, 5, 6, 7);
                    o[db][nb] = mfma32(af, bf_, o[db][nb]);
                }
            }
        }
    }

    // epilogue: out[b, q, hh*64 + d] = O^T[d][q] / l
#pragma unroll
    for (int nb = 0; nb < 2; ++nb) {
        float linv = 1.f / l_i[nb];
        int q = qt * 128 + w * 32 + nb * 16 + c;
#pragma unroll
        for (int db = 0; db < 4; ++db) {
            f32x4 v = o[db][nb] * linv;
            *(f32x4*)(out + ((size_t)b * S_ + q) * H_ + hh * 64 + db * 16 + quad * 4) = v;
        }
    }
}

// ---------------- launch ----------------
extern "C" void kernel_launch(void* const* d_in, const int* in_sizes, int n_in,
                              void* d_out, int out_size, void* d_ws, size_t ws_size,
                              hipStream_t stream) {
    const float* query = (const float*)d_in[0];
    const float* key   = (const float*)d_in[1];
    const float* value = (const float*)d_in[2];
    const float* mask  = (const float*)d_in[3];
    const float* Wq    = (const float*)d_in[4];
    const float* bq    = (const float*)d_in[5];
    const float* Wk    = (const float*)d_in[6];
    const float* bk    = (const float*)d_in[7];
    const float* Wv    = (const float*)d_in[8];
    const float* bv    = (const float*)d_in[9];
    float* out = (float*)d_out;

    bf16* p = (bf16*)d_ws;
    bf16* xqh = p; p += SZX; bf16* xql = p; p += SZX;
    bf16* xkh = p; p += SZX; bf16* xkl = p; p += SZX;
    bf16* xvh = p; p += SZX; bf16* xvl = p; p += SZX;
    bf16* wqh = p; p += SZW; bf16* wql = p; p += SZW;
    bf16* wkh = p; p += SZW; bf16* wkl = p; p += SZW;
    bf16* wvh = p; p += SZW; bf16* wvl = p; p += SZW;
    bf16* qh  = p; p += SZX; bf16* ql  = p; p += SZX;
    bf16* kh  = p; p += SZX; bf16* kl  = p; p += SZX;
    bf16* vh  = p; p += SZX; bf16* vt  = p; p += SZX;
    // total: 12*SZX + 6*SZW elems * 2B = 113,246,208 bytes

    dim3 sx((int)(SZX / 4 + 255) / 256, 3);
    split3_kernel<<<sx, 256, 0, stream>>>(query, key, value, xqh, xql, xkh, xkl, xvh, xvl, (int)(SZX / 4));
    dim3 sw((int)(SZW / 4 + 255) / 256, 3);
    split3_kernel<<<sw, 256, 0, stream>>>(Wq, Wk, Wv, wqh, wql, wkh, wkl, wvh, wvl, (int)(SZW / 4));

    dim3 pg(24, M_ / 128);
    proj_kernel<<<pg, 256, 0, stream>>>(xqh, xql, xkh, xkl, xvh, xvl,
                                        wqh, wql, wkh, wkl, wvh, wvl,
                                        bq, bk, bv, qh, ql, kh, kl, vh);

    dim3 tg(S_ / 64, B_ * NH_);
    transpose_v<<<tg, 256, 0, stream>>>(vh, vt);

    dim3 ag(S_ / 128, B_ * NH_);
    attn_kernel<<<ag, 256, 0, stream>>>(qh, ql, kh, kl, vt, mask, out);
}

// Round 3
// 245.356 us; speedup vs baseline: 2.0600x; 1.2111x over previous
//
#include <hip/hip_runtime.h>
#include <math.h>

using f16 = _Float16;
using f16x4 = __attribute__((ext_vector_type(4))) _Float16;
using f16x8 = __attribute__((ext_vector_type(8))) _Float16;
using f32x4 = __attribute__((ext_vector_type(4))) float;

static constexpr int B_ = 2, S_ = 2048, H_ = 1024, NH_ = 16, HD_ = 64;
static constexpr int M_ = B_ * S_;                 // 4096 rows of X
static constexpr size_t SZX = (size_t)M_ * H_;     // 4,194,304 elems
static constexpr size_t SZW = (size_t)H_ * H_;     // 1,048,576 elems
static constexpr float LOG2E = 1.4426950408889634f;

__device__ __forceinline__ f32x4 mfma16(f16x8 a, f16x8 b, f32x4 c) {
    return __builtin_amdgcn_mfma_f32_16x16x32_f16(a, b, c, 0, 0, 0);
}

// async 16B global -> LDS (wave-uniform LDS base + lane*16)
typedef const __attribute__((address_space(1))) unsigned int* gas_t;
typedef __attribute__((address_space(3))) unsigned int* las_t;
__device__ __forceinline__ void load16_lds(const f16* g, f16* lds_base) {
    __builtin_amdgcn_global_load_lds((gas_t)g, (las_t)lds_base, 16, 0, 0);
}

// ---------------- convert fp32 -> fp16 (3 tensors per launch) --------------
__global__ __launch_bounds__(256) void cvt3_kernel(
    const float* __restrict__ a0, const float* __restrict__ a1, const float* __restrict__ a2,
    f16* __restrict__ o0, f16* __restrict__ o1, f16* __restrict__ o2, int n4) {
    int z = blockIdx.y;
    const float* x = z == 0 ? a0 : z == 1 ? a1 : a2;
    f16* o = z == 0 ? o0 : z == 1 ? o1 : o2;
    int i = blockIdx.x * 256 + threadIdx.x;
    if (i >= n4) return;
    f32x4 v = ((const f32x4*)x)[i];
    f16x4 h;
#pragma unroll
    for (int j = 0; j < 4; ++j) h[j] = (f16)v[j];
    ((f16x4*)o)[i] = h;
}

// ---------------- fused QKV projection GEMM (single fp16, m97 structure) ---
// O[m,n] = sum_k X[m,k] W[n,k] + b[n]. Tile 128x128, BK=64, 4 waves x 64x64.
// which = blockIdx.x>>3 selects q/k/v. q pre-scaled by log2e/8 (exp2-domain
// softmax). q,k written [B,NH,S,HD] scalar; v written transposed [B,NH,HD,S]
// with contiguous half4 stores (C-layout rows are s-contiguous).
__global__ __launch_bounds__(256, 2) void proj_kernel(
    const f16* __restrict__ xq, const f16* __restrict__ xk, const f16* __restrict__ xv,
    const f16* __restrict__ wq, const f16* __restrict__ wk, const f16* __restrict__ wv,
    const float* __restrict__ bq, const float* __restrict__ bk, const float* __restrict__ bv,
    f16* __restrict__ q, f16* __restrict__ k, f16* __restrict__ vt) {
    __shared__ alignas(16) f16 sX[128][64];
    __shared__ alignas(16) f16 sW[128][64];

    const int t = threadIdx.x, w = t >> 6, lane = t & 63, c = lane & 15, quad = lane >> 4;
    const int which = blockIdx.x >> 3;
    const int col0 = (blockIdx.x & 7) * 128;
    const int row0 = blockIdx.y * 128;
    const f16* X = which == 0 ? xq : which == 1 ? xk : xv;
    const f16* W = which == 0 ? wq : which == 1 ? wk : wv;

    const int wm = (w & 1) * 64, wn = (w >> 1) * 64;
    f32x4 acc[4][4] = {};

    for (int k0 = 0; k0 < H_; k0 += 64) {
        if (k0) __syncthreads();
#pragma unroll
        for (int i = 0; i < 4; ++i) {
            int r = 8 * w + 32 * i + (lane >> 3);
            int cb = (lane & 7) ^ ((lane >> 3) & 7);   // XOR swizzle folded into global addr
            load16_lds(X + (size_t)(row0 + r) * H_ + k0 + cb * 8, &sX[8 * w + 32 * i][0]);
            load16_lds(W + (size_t)(col0 + r) * H_ + k0 + cb * 8, &sW[8 * w + 32 * i][0]);
        }
        __syncthreads();
#pragma unroll
        for (int ks = 0; ks < 2; ++ks) {
            const int ph = ((ks * 4 + quad) ^ (c & 7)) * 8;
            f16x8 bf[4];
#pragma unroll
            for (int ng = 0; ng < 4; ++ng) bf[ng] = *(const f16x8*)&sW[wn + ng * 16 + c][ph];
#pragma unroll
            for (int mg = 0; mg < 4; ++mg) {
                f16x8 af = *(const f16x8*)&sX[wm + mg * 16 + c][ph];
#pragma unroll
                for (int ng = 0; ng < 4; ++ng) acc[mg][ng] = mfma16(af, bf[ng], acc[mg][ng]);
            }
        }
    }

    const float* bias = which == 0 ? bq : which == 1 ? bk : bv;
    const float scale = which == 0 ? (LOG2E * 0.125f) : 1.0f;
#pragma unroll
    for (int ng = 0; ng < 4; ++ng) {
        int col = col0 + wn + ng * 16 + c;
        float bv_ = bias[col];
        int hh = col >> 6, d = col & 63;
#pragma unroll
        for (int mg = 0; mg < 4; ++mg) {
            int rbase = row0 + wm + mg * 16 + quad * 4;
            int bb = rbase >> 11, ss = rbase & (S_ - 1);
            if (which == 2) {
                f16x4 pv;
#pragma unroll
                for (int r4 = 0; r4 < 4; ++r4) pv[r4] = (f16)(acc[mg][ng][r4] + bv_);
                *(f16x4*)(vt + ((size_t)(bb * NH_ + hh) * HD_ + d) * S_ + ss) = pv;
            } else {
                f16* O = which == 0 ? q : k;
#pragma unroll
                for (int r4 = 0; r4 < 4; ++r4) {
                    float v = (acc[mg][ng][r4] + bv_) * scale;
                    O[((size_t)(bb * NH_ + hh) * S_ + ss + r4) * HD_ + d] = (f16)v;
                }
            }
        }
    }
}

// ---------------- flash attention (S^T formulation, all fp16, exp2 domain) --
// block: (q-tile 128, bh). 4 waves x 32 q. Q frags in registers.
// S^T = K·Q^T; softmax per q-column; O^T = V^T·P^T with P in registers.
__global__ __launch_bounds__(256, 2) void attn_kernel(
    const f16* __restrict__ Q, const f16* __restrict__ K,
    const f16* __restrict__ VT, const float* __restrict__ mask,
    float* __restrict__ out) {
    __shared__ alignas(16) f16 sK[64][64];
    __shared__ alignas(16) f16 sVT[64][64];   // [d][key]

    const int t = threadIdx.x, w = t >> 6, lane = t & 63, c = lane & 15, quad = lane >> 4;
    const int qt = blockIdx.x, bh = blockIdx.y;
    const int b = bh >> 4, hh = bh & 15;
    const size_t qkb = (size_t)bh * S_ * HD_;
    const size_t vtb = (size_t)bh * HD_ * S_;

    // Q fragments (registers, whole K-loop): [nb][ch]
    f16x8 qf[2][2];
#pragma unroll
    for (int nb = 0; nb < 2; ++nb)
#pragma unroll
        for (int ch = 0; ch < 2; ++ch) {
            int qq = qt * 128 + w * 32 + nb * 16 + c;
            qf[nb][ch] = *(const f16x8*)(Q + qkb + (size_t)qq * HD_ + ch * 32 + quad * 8);
        }

    f32x4 o[4][2] = {};
    float m_i[2] = {-INFINITY, -INFINITY};
    float l_i[2] = {0.f, 0.f};

    for (int kt = 0; kt < S_ / 64; ++kt) {
        if (kt) __syncthreads();
#pragma unroll
        for (int i = 0; i < 2; ++i) {
            int r = 8 * w + 32 * i + (lane >> 3);
            int cb = (lane & 7) ^ ((lane >> 3) & 7);
            load16_lds(K + qkb + (size_t)(kt * 64 + r) * HD_ + cb * 8, &sK[8 * w + 32 * i][0]);
            load16_lds(VT + vtb + (size_t)r * S_ + kt * 64 + cb * 8, &sVT[8 * w + 32 * i][0]);
        }
        __syncthreads();

        // S^T[key][q] (log2 domain: q pre-scaled by log2e/8)
        f32x4 s[4][2] = {};
#pragma unroll
        for (int ch = 0; ch < 2; ++ch) {
#pragma unroll
            for (int mb = 0; mb < 4; ++mb) {
                int ph = ((ch * 4 + quad) ^ (c & 7)) * 8;
                f16x8 ah = *(const f16x8*)&sK[mb * 16 + c][ph];
#pragma unroll
                for (int nb = 0; nb < 2; ++nb) s[mb][nb] = mfma16(ah, qf[nb][ch], s[mb][nb]);
            }
        }

        f32x4 mk[4];
#pragma unroll
        for (int mb = 0; mb < 4; ++mb)
            mk[mb] = *(const f32x4*)(mask + b * S_ + kt * 64 + mb * 16 + quad * 4) * LOG2E;

        f16x4 pf[4][2];   // P fragments [16-key chunk][nb]
#pragma unroll
        for (int nb = 0; nb < 2; ++nb) {
            float sv[4][4];
            float rm = -INFINITY;
#pragma unroll
            for (int mb = 0; mb < 4; ++mb)
#pragma unroll
                for (int r = 0; r < 4; ++r) {
                    float x = s[mb][nb][r] + mk[mb][r];
                    sv[mb][r] = x;
                    rm = fmaxf(rm, x);
                }
            rm = fmaxf(rm, __shfl_xor(rm, 16));
            rm = fmaxf(rm, __shfl_xor(rm, 32));
            float mnew = fmaxf(m_i[nb], rm);
            float alpha = exp2f(m_i[nb] - mnew);   // first iter: exp2(-inf)=0
            m_i[nb] = mnew;
            float rs = 0.f;
#pragma unroll
            for (int mb = 0; mb < 4; ++mb)
#pragma unroll
                for (int r = 0; r < 4; ++r) {
                    float p = exp2f(sv[mb][r] - mnew);
                    sv[mb][r] = p;
                    rs += p;
                }
            rs += __shfl_xor(rs, 16);
            rs += __shfl_xor(rs, 32);
            l_i[nb] = l_i[nb] * alpha + rs;
#pragma unroll
            for (int db = 0; db < 4; ++db) o[db][nb] *= alpha;
#pragma unroll
            for (int mb = 0; mb < 4; ++mb) {
                f16x4 p4;
#pragma unroll
                for (int r = 0; r < 4; ++r) p4[r] = (f16)sv[mb][r];
                pf[mb][nb] = p4;
            }
        }

        // O^T += V^T · P^T : pack two 16-key chunks into one K=32 MFMA
#pragma unroll
        for (int kcc = 0; kcc < 2; ++kcc) {
#pragma unroll
            for (int db = 0; db < 4; ++db) {
                int row = db * 16 + c;
                f16x4 a0 = *(const f16x4*)&sVT[row][((4 * kcc + (quad >> 1)) ^ (c & 7)) * 8 + (quad & 1) * 4];
                f16x4 a1 = *(const f16x4*)&sVT[row][((4 * kcc + 2 + (quad >> 1)) ^ (c & 7)) * 8 + (quad & 1) * 4];
                f16x8 af = __builtin_shufflevector(a0, a1, 0, 1, 2, 3, 4, 5, 6, 7);
#pragma unroll
                for (int nb = 0; nb < 2; ++nb) {
                    f16x8 bf_ = __builtin_shufflevector(pf[2 * kcc][nb], pf[2 * kcc + 1][nb], 0, 1, 2, 3, 4, 5, 6, 7);
                    o[db][nb] = mfma16(af, bf_, o[db][nb]);
                }
            }
        }
    }

    // epilogue: out[b, q, hh*64 + d] = O^T[d][q] / l
#pragma unroll
    for (int nb = 0; nb < 2; ++nb) {
        float linv = 1.f / l_i[nb];
        int qq = qt * 128 + w * 32 + nb * 16 + c;
#pragma unroll
        for (int db = 0; db < 4; ++db) {
            f32x4 v = o[db][nb] * linv;
            *(f32x4*)(out + ((size_t)b * S_ + qq) * H_ + hh * 64 + db * 16 + quad * 4) = v;
        }
    }
}

// ---------------- launch ----------------
extern "C" void kernel_launch(void* const* d_in, const int* in_sizes, int n_in,
                              void* d_out, int out_size, void* d_ws, size_t ws_size,
                              hipStream_t stream) {
    const float* query = (const float*)d_in[0];
    const float* key   = (const float*)d_in[1];
    const float* value = (const float*)d_in[2];
    const float* mask  = (const float*)d_in[3];
    const float* Wq    = (const float*)d_in[4];
    const float* bq    = (const float*)d_in[5];
    const float* Wk    = (const float*)d_in[6];
    const float* bk    = (const float*)d_in[7];
    const float* Wv    = (const float*)d_in[8];
    const float* bv    = (const float*)d_in[9];
    float* out = (float*)d_out;

    f16* p = (f16*)d_ws;
    f16* xq = p; p += SZX; f16* xk = p; p += SZX; f16* xv = p; p += SZX;
    f16* wq = p; p += SZW; f16* wk = p; p += SZW; f16* wv = p; p += SZW;
    f16* q  = p; p += SZX; f16* k  = p; p += SZX; f16* vt = p; p += SZX;
    // total: 6*SZX + 3*SZW elems * 2B = 56,623,104 bytes

    dim3 sx((int)(SZX / 4 + 255) / 256, 3);
    cvt3_kernel<<<sx, 256, 0, stream>>>(query, key, value, xq, xk, xv, (int)(SZX / 4));
    dim3 sw((int)(SZW / 4 + 255) / 256, 3);
    cvt3_kernel<<<sw, 256, 0, stream>>>(Wq, Wk, Wv, wq, wk, wv, (int)(SZW / 4));

    dim3 pg(24, M_ / 128);
    proj_kernel<<<pg, 256, 0, stream>>>(xq, xk, xv, wq, wk, wv, bq, bk, bv, q, k, vt);

    dim3 ag(S_ / 128, B_ * NH_);
    attn_kernel<<<ag, 256, 0, stream>>>(q, k, vt, mask, out);
}

// Round 4
// 236.261 us; speedup vs baseline: 2.1393x; 1.0385x over previous
//
#include <hip/hip_runtime.h>
#include <math.h>

using f16 = _Float16;
using f16x4 = __attribute__((ext_vector_type(4))) _Float16;
using f16x8 = __attribute__((ext_vector_type(8))) _Float16;
using f32x4 = __attribute__((ext_vector_type(4))) float;

static constexpr int B_ = 2, S_ = 2048, H_ = 1024, NH_ = 16, HD_ = 64;
static constexpr int M_ = B_ * S_;                 // 4096 rows of X
static constexpr size_t SZX = (size_t)M_ * H_;     // 4,194,304 elems
static constexpr size_t SZW = (size_t)H_ * H_;     // 1,048,576 elems
static constexpr float LOG2E = 1.4426950408889634f;

__device__ __forceinline__ f32x4 mfma16(f16x8 a, f16x8 b, f32x4 c) {
    return __builtin_amdgcn_mfma_f32_16x16x32_f16(a, b, c, 0, 0, 0);
}
__device__ __forceinline__ f32x4 vmax4(f32x4 a, f32x4 b) {
    f32x4 r;
#pragma unroll
    for (int j = 0; j < 4; ++j) r[j] = fmaxf(a[j], b[j]);
    return r;
}

// async 16B global -> LDS (wave-uniform LDS base + lane*16)
typedef const __attribute__((address_space(1))) unsigned int* gas_t;
typedef __attribute__((address_space(3))) unsigned int* las_t;
__device__ __forceinline__ void load16_lds(const f16* g, f16* lds_base) {
    __builtin_amdgcn_global_load_lds((gas_t)g, (las_t)lds_base, 16, 0, 0);
}

// ---------------- convert fp32 -> fp16 (3 tensors per launch) --------------
__global__ __launch_bounds__(256) void cvt3_kernel(
    const float* __restrict__ a0, const float* __restrict__ a1, const float* __restrict__ a2,
    f16* __restrict__ o0, f16* __restrict__ o1, f16* __restrict__ o2, int n4) {
    int z = blockIdx.y;
    const float* x = z == 0 ? a0 : z == 1 ? a1 : a2;
    f16* o = z == 0 ? o0 : z == 1 ? o1 : o2;
    int i = blockIdx.x * 256 + threadIdx.x;
    if (i >= n4) return;
    f32x4 v = ((const f32x4*)x)[i];
    f16x4 h;
#pragma unroll
    for (int j = 0; j < 4; ++j) h[j] = (f16)v[j];
    ((f16x4*)o)[i] = h;
}

// ---------------- mask * log2e -------------------------------------------
__global__ __launch_bounds__(256) void maskscale_kernel(const float* __restrict__ m,
                                                        float* __restrict__ o, int n) {
    int i = blockIdx.x * 256 + threadIdx.x;
    if (i < n) o[i] = m[i] * LOG2E;
}

// ---------------- Q/K projection: O^T = W·X^T orientation ------------------
// A = W rows (M-dim = d-cols), B = X rows (N-dim = s-rows). C-layout then has
// 4 consecutive d per lane -> vectorized f16x4 stores into [B,NH,S,HD].
// which = blockIdx.x>>3 in {0:q, 1:k}. q pre-scaled by log2e/8.
__global__ __launch_bounds__(256, 2) void projqk_kernel(
    const f16* __restrict__ xq, const f16* __restrict__ xk,
    const f16* __restrict__ wq, const f16* __restrict__ wk,
    const float* __restrict__ bq, const float* __restrict__ bk,
    f16* __restrict__ q, f16* __restrict__ k) {
    __shared__ alignas(16) f16 sX[128][64];
    __shared__ alignas(16) f16 sW[128][64];
    const int t = threadIdx.x, w = t >> 6, lane = t & 63, c = lane & 15, quad = lane >> 4;
    const int which = blockIdx.x >> 3;
    const int col0 = (blockIdx.x & 7) * 128;
    const int row0 = blockIdx.y * 128;
    const f16* X = which ? xk : xq;
    const f16* W = which ? wk : wq;
    const int wm = (w & 1) * 64, wn = (w >> 1) * 64;
    f32x4 acc[4][4] = {};

    for (int k0 = 0; k0 < H_; k0 += 64) {
        if (k0) __syncthreads();
#pragma unroll
        for (int i = 0; i < 4; ++i) {
            int r = 8 * w + 32 * i + (lane >> 3);
            int cb = (lane & 7) ^ ((lane >> 3) & 7);
            load16_lds(X + (size_t)(row0 + r) * H_ + k0 + cb * 8, &sX[8 * w + 32 * i][0]);
            load16_lds(W + (size_t)(col0 + r) * H_ + k0 + cb * 8, &sW[8 * w + 32 * i][0]);
        }
        __syncthreads();
#pragma unroll
        for (int ks = 0; ks < 2; ++ks) {
            const int ph = ((ks * 4 + quad) ^ (c & 7)) * 8;
            f16x8 wf[4], xf[4];
#pragma unroll
            for (int g = 0; g < 4; ++g) {
                wf[g] = *(const f16x8*)&sW[wn + g * 16 + c][ph];
                xf[g] = *(const f16x8*)&sX[wm + g * 16 + c][ph];
            }
#pragma unroll
            for (int mg = 0; mg < 4; ++mg)
#pragma unroll
                for (int ng = 0; ng < 4; ++ng)
                    acc[mg][ng] = mfma16(wf[ng], xf[mg], acc[mg][ng]);
        }
    }

    const float* bias = which ? bk : bq;
    f16* O = which ? k : q;
    const float scale = which ? 1.0f : (LOG2E * 0.125f);
#pragma unroll
    for (int ng = 0; ng < 4; ++ng) {
        int col4 = col0 + wn + ng * 16 + quad * 4;
        f32x4 bv = *(const f32x4*)(bias + col4);
        int hh = col4 >> 6, d = col4 & 63;
#pragma unroll
        for (int mg = 0; mg < 4; ++mg) {
            int rowg = row0 + wm + mg * 16 + c;
            int bb = rowg >> 11, ss = rowg & (S_ - 1);
            f16x4 ov;
#pragma unroll
            for (int r = 0; r < 4; ++r) ov[r] = (f16)((acc[mg][ng][r] + bv[r]) * scale);
            *(f16x4*)(O + ((size_t)(bb * NH_ + hh) * S_ + ss) * HD_ + d) = ov;
        }
    }
}

// ---------------- V projection: original orientation, transposed permuted out
// vt[bh][d][s'] with s' = s bit-permuted within 32-groups:
// p1p0=k1k0, p2=k4, p3=k2, p4=k3 — makes attention's PV A-frag a single b128.
__global__ __launch_bounds__(256, 2) void projv_kernel(
    const f16* __restrict__ xv, const f16* __restrict__ wv,
    const float* __restrict__ bvp, f16* __restrict__ vt) {
    __shared__ alignas(16) f16 sX[128][64];
    __shared__ alignas(16) f16 sW[128][64];
    const int t = threadIdx.x, w = t >> 6, lane = t & 63, c = lane & 15, quad = lane >> 4;
    const int col0 = blockIdx.x * 128;
    const int row0 = blockIdx.y * 128;
    const int wm = (w & 1) * 64, wn = (w >> 1) * 64;
    f32x4 acc[4][4] = {};

    for (int k0 = 0; k0 < H_; k0 += 64) {
        if (k0) __syncthreads();
#pragma unroll
        for (int i = 0; i < 4; ++i) {
            int r = 8 * w + 32 * i + (lane >> 3);
            int cb = (lane & 7) ^ ((lane >> 3) & 7);
            load16_lds(xv + (size_t)(row0 + r) * H_ + k0 + cb * 8, &sX[8 * w + 32 * i][0]);
            load16_lds(wv + (size_t)(col0 + r) * H_ + k0 + cb * 8, &sW[8 * w + 32 * i][0]);
        }
        __syncthreads();
#pragma unroll
        for (int ks = 0; ks < 2; ++ks) {
            const int ph = ((ks * 4 + quad) ^ (c & 7)) * 8;
            f16x8 wf[4], xf[4];
#pragma unroll
            for (int g = 0; g < 4; ++g) {
                wf[g] = *(const f16x8*)&sW[wn + g * 16 + c][ph];
                xf[g] = *(const f16x8*)&sX[wm + g * 16 + c][ph];
            }
#pragma unroll
            for (int mg = 0; mg < 4; ++mg)
#pragma unroll
                for (int ng = 0; ng < 4; ++ng)
                    acc[mg][ng] = mfma16(xf[mg], wf[ng], acc[mg][ng]);
        }
    }

#pragma unroll
    for (int ng = 0; ng < 4; ++ng) {
        int col = col0 + wn + ng * 16 + c;
        float bv_ = bvp[col];
        int hh = col >> 6, d = col & 63;
#pragma unroll
        for (int mg = 0; mg < 4; ++mg) {
            int rbase = row0 + wm + mg * 16 + quad * 4;
            int bb = rbase >> 11, ss = rbase & (S_ - 1);
            int sl = ss & 31;   // 4-aligned: k1k0 = 0
            int pp = (ss & ~31) | (((sl >> 4) & 1) << 2) | (((sl >> 2) & 1) << 3) | (((sl >> 3) & 1) << 4);
            f16x4 ov;
#pragma unroll
            for (int r = 0; r < 4; ++r) ov[r] = (f16)(acc[mg][ng][r] + bv_);
            *(f16x4*)(vt + ((size_t)(bb * NH_ + hh) * HD_ + d) * S_ + pp) = ov;
        }
    }
}

// ---------------- flash attention (S^T, fp16, exp2, K-tile 128) ------------
__global__ __launch_bounds__(256, 2) void attn_kernel(
    const f16* __restrict__ Q, const f16* __restrict__ K,
    const f16* __restrict__ VT, const float* __restrict__ mask_s,
    float* __restrict__ out) {
    __shared__ alignas(16) f16 sK[128][64];
    __shared__ alignas(16) f16 sVT[64][128];   // [d][key-permuted]

    const int t = threadIdx.x, w = t >> 6, lane = t & 63, c = lane & 15, quad = lane >> 4;
    const int qt = blockIdx.x, bh = blockIdx.y;
    const int b = bh >> 4, hh = bh & 15;
    const size_t qkb = (size_t)bh * S_ * HD_;
    const size_t vtb = (size_t)bh * HD_ * S_;

    // Q fragments (registers, whole K-loop)
    f16x8 qf[2][2];
#pragma unroll
    for (int nb = 0; nb < 2; ++nb)
#pragma unroll
        for (int ch = 0; ch < 2; ++ch) {
            int qq = qt * 128 + w * 32 + nb * 16 + c;
            qf[nb][ch] = *(const f16x8*)(Q + qkb + (size_t)qq * HD_ + ch * 32 + quad * 8);
        }

    // precomputed staging addresses (iter-invariant parts)
    const int kr = 8 * w + (lane >> 3);
    const int kcb = (lane & 7) ^ ((lane >> 3) & 7);
    const f16* kbase = K + qkb + (size_t)kr * HD_ + kcb * 8;
    const int vr = 4 * w + (lane >> 4);
    const int vlb = (lane & 8) | (((lane & 7) ^ vr) & 7);
    const f16* vtbase = VT + vtb + (size_t)vr * S_ + vlb * 8;
    const float* mbase = mask_s + b * S_;

    f32x4 o[4][2] = {};
    float m_i[2] = {-INFINITY, -INFINITY};
    float l_i[2] = {0.f, 0.f};

    for (int kt = 0; kt < S_ / 128; ++kt) {
        if (kt) __syncthreads();
#pragma unroll
        for (int i = 0; i < 4; ++i) {
            load16_lds(kbase + (size_t)(kt * 128 + 32 * i) * HD_, &sK[8 * w + 32 * i][0]);
            load16_lds(vtbase + (size_t)(16 * i) * S_ + kt * 128, &sVT[4 * w + 16 * i][0]);
        }
        // S^T init = scaled mask (accumulator trick)
        f32x4 s[8][2];
#pragma unroll
        for (int mb = 0; mb < 8; ++mb) {
            f32x4 mv = *(const f32x4*)(mbase + kt * 128 + mb * 16 + quad * 4);
            s[mb][0] = mv;
            s[mb][1] = mv;
        }
        __syncthreads();

        // S^T[key][q] += K·Q^T
#pragma unroll
        for (int ch = 0; ch < 2; ++ch) {
            const int ph = ((ch * 4 + quad) ^ (c & 7)) * 8;
#pragma unroll
            for (int mb = 0; mb < 8; ++mb) {
                f16x8 ah = *(const f16x8*)&sK[mb * 16 + c][ph];
#pragma unroll
                for (int nb = 0; nb < 2; ++nb) s[mb][nb] = mfma16(ah, qf[nb][ch], s[mb][nb]);
            }
        }

        // online softmax (per q-column), P -> registers
        f16x4 pf[8][2];
#pragma unroll
        for (int nb = 0; nb < 2; ++nb) {
            f32x4 t0 = vmax4(vmax4(s[0][nb], s[1][nb]), vmax4(s[2][nb], s[3][nb]));
            f32x4 t1 = vmax4(vmax4(s[4][nb], s[5][nb]), vmax4(s[6][nb], s[7][nb]));
            f32x4 tm = vmax4(t0, t1);
            float rm = fmaxf(fmaxf(tm[0], tm[1]), fmaxf(tm[2], tm[3]));
            rm = fmaxf(rm, __shfl_xor(rm, 16));
            rm = fmaxf(rm, __shfl_xor(rm, 32));
            float mnew = fmaxf(m_i[nb], rm);
            float alpha = exp2f(m_i[nb] - mnew);   // first iter: exp2(-inf)=0
            m_i[nb] = mnew;
            f32x4 psum = {0.f, 0.f, 0.f, 0.f};
#pragma unroll
            for (int mb = 0; mb < 8; ++mb) {
                f32x4 pv;
#pragma unroll
                for (int r = 0; r < 4; ++r) {
                    float p = exp2f(s[mb][nb][r] - mnew);
                    pv[r] = p;
                    pf[mb][nb][r] = (f16)p;
                }
                psum += pv;
            }
            float rs = (psum[0] + psum[1]) + (psum[2] + psum[3]);
            rs += __shfl_xor(rs, 16);
            rs += __shfl_xor(rs, 32);
            l_i[nb] = l_i[nb] * alpha + rs;
#pragma unroll
            for (int db = 0; db < 4; ++db) o[db][nb] *= alpha;
        }

        // O^T += V^T·P^T  (A single b128 via permuted VT; P register-resident)
#pragma unroll
        for (int kcc = 0; kcc < 4; ++kcc) {
            const int blk = kcc * 4 + quad;
            const int pblk = (blk & 8) | ((blk ^ c) & 7);
#pragma unroll
            for (int db = 0; db < 4; ++db) {
                f16x8 af = *(const f16x8*)&sVT[db * 16 + c][pblk * 8];
#pragma unroll
                for (int nb = 0; nb < 2; ++nb) {
                    f16x8 bf_ = __builtin_shufflevector(pf[2 * kcc][nb], pf[2 * kcc + 1][nb],
                                                        0, 1, 2, 3, 4, 5, 6, 7);
                    o[db][nb] = mfma16(af, bf_, o[db][nb]);
                }
            }
        }
    }

    // epilogue: out[b, q, hh*64 + d] = O^T[d][q] / l
#pragma unroll
    for (int nb = 0; nb < 2; ++nb) {
        float linv = 1.f / l_i[nb];
        int qq = qt * 128 + w * 32 + nb * 16 + c;
#pragma unroll
        for (int db = 0; db < 4; ++db) {
            f32x4 v = o[db][nb] * linv;
            *(f32x4*)(out + ((size_t)b * S_ + qq) * H_ + hh * 64 + db * 16 + quad * 4) = v;
        }
    }
}

// ---------------- launch ----------------
extern "C" void kernel_launch(void* const* d_in, const int* in_sizes, int n_in,
                              void* d_out, int out_size, void* d_ws, size_t ws_size,
                              hipStream_t stream) {
    const float* query = (const float*)d_in[0];
    const float* key   = (const float*)d_in[1];
    const float* value = (const float*)d_in[2];
    const float* mask  = (const float*)d_in[3];
    const float* Wq    = (const float*)d_in[4];
    const float* bq    = (const float*)d_in[5];
    const float* Wk    = (const float*)d_in[6];
    const float* bk    = (const float*)d_in[7];
    const float* Wv    = (const float*)d_in[8];
    const float* bv    = (const float*)d_in[9];
    float* out = (float*)d_out;

    f16* p = (f16*)d_ws;
    f16* xq = p; p += SZX; f16* xk = p; p += SZX; f16* xv = p; p += SZX;
    f16* wq = p; p += SZW; f16* wk = p; p += SZW; f16* wv = p; p += SZW;
    f16* q  = p; p += SZX; f16* k  = p; p += SZX; f16* vt = p; p += SZX;
    float* mask_s = (float*)p;   // B_*S_ floats

    dim3 sx((int)(SZX / 4 + 255) / 256, 3);
    cvt3_kernel<<<sx, 256, 0, stream>>>(query, key, value, xq, xk, xv, (int)(SZX / 4));
    dim3 sw((int)(SZW / 4 + 255) / 256, 3);
    cvt3_kernel<<<sw, 256, 0, stream>>>(Wq, Wk, Wv, wq, wk, wv, (int)(SZW / 4));
    maskscale_kernel<<<(B_ * S_ + 255) / 256, 256, 0, stream>>>(mask, mask_s, B_ * S_);

    dim3 pqk(16, M_ / 128);
    projqk_kernel<<<pqk, 256, 0, stream>>>(xq, xk, wq, wk, bq, bk, q, k);
    dim3 pv(8, M_ / 128);
    projv_kernel<<<pv, 256, 0, stream>>>(xv, wv, bv, vt);

    dim3 ag(S_ / 128, B_ * NH_);
    attn_kernel<<<ag, 256, 0, stream>>>(q, k, vt, mask_s, out);
}